// Round 12
// baseline (890.376 us; speedup 1.0000x reference)
//
#include <hip/hip_runtime.h>
#include <stdint.h>
#include <stddef.h>

// ---------------------------------------------------------------------------
// EnhancedSpatialAttention, round 12 (MI355X / gfx950).
// K2 = attn_qkv2 rebuilt on r11's 2-seq/block skeleton:
//  - 24KB bodies (Q+K+V chunks of one kc staged together), ring-2 x 24KB,
//    64 bodies/block, uniform counted wait vmcnt(11), 1 barrier/body.
//  - xa (A-frags) double-buffered in registers: xa(kc+1) issued during kc
//    -> full body of flight over HBM latency (r11 exposed ~900cyc per kc).
//  - attn scratch OVERLAYS the weight ring (ring idle during attn; next
//    head staged after a post-copyout barrier) -> static LDS 54KB ->
//    2 blocks/CU (4 waves/SIMD), cross-block latency hiding.
//  - b2d bias loaded per-head during attn (keeps persistent VGPR ~125 < 128).
// prep / oproj_ln: verbatim r11 (proven).
// ---------------------------------------------------------------------------

typedef __attribute__((ext_vector_type(8))) short short8;    // 8 bf16
typedef __attribute__((ext_vector_type(4))) float f32x4;     // MFMA C/D frag

typedef __attribute__((address_space(3))) unsigned int as3_u32;
typedef __attribute__((address_space(1))) unsigned int as1_u32;

#define VMCNT11 asm volatile("s_waitcnt vmcnt(11)" ::: "memory")
#define VMCNT5  asm volatile("s_waitcnt vmcnt(5)" ::: "memory")
#define VMCNT0  asm volatile("s_waitcnt vmcnt(0)" ::: "memory")
#define LGKM0   asm volatile("s_waitcnt lgkmcnt(0)" ::: "memory")
#define BARR()  __builtin_amdgcn_s_barrier()
#define PRIO1   __builtin_amdgcn_s_setprio(1)
#define PRIO0   __builtin_amdgcn_s_setprio(0)

__device__ __forceinline__ unsigned short f2bf(float f) {
  unsigned u = __builtin_bit_cast(unsigned, f);
  u = (u + 0x7FFFu + ((u >> 16) & 1u)) >> 16;   // RNE
  return (unsigned short)u;
}

__device__ __forceinline__ f32x4 mfma16(short8 a, short8 b, f32x4 c) {
  return __builtin_amdgcn_mfma_f32_16x16x32_bf16(a, b, c, 0, 0, 0);
}

// 64-row x 64-col bf16 scratch, 128B row stride, 16B-unit XOR swizzle.
__device__ __forceinline__ short8 rd8s(const char* buf, int row, int unit) {
  return *(const short8*)(buf + row * 128 + ((unit ^ (row & 7)) * 16));
}
__device__ __forceinline__ void wr2s(char* buf, int row, int col, unsigned short v) {
  int slot = (col >> 3) ^ (row & 7);
  *(unsigned short*)(buf + row * 128 + slot * 16 + (col & 7) * 2) = v;
}
__device__ __forceinline__ void wr8s(char* buf, int row, int col, uint2 v) {
  int slot = (col >> 3) ^ (row & 7);
  *(uint2*)(buf + row * 128 + slot * 16 + (col & 7) * 2) = v;
}

// 512-thread staging: one 8KB chunk, 1 global_load_lds per thread.
__device__ __forceinline__ void stage8w(char* lds, const char* gsrc, int w, int lane) {
  __builtin_amdgcn_global_load_lds((const as1_u32*)(gsrc + w * 1024 + lane * 16),
                                   (as3_u32*)(lds + w * 1024), 16, 0, 0);
}
// 24KB = 3 consecutive 8KB chunks (3 vmem ops/wave).
__device__ __forceinline__ void stage24(char* lds, const char* gsrc, int w, int lane) {
  stage8w(lds, gsrc, w, lane);
  stage8w(lds + 8192, gsrc + 8192, w, lane);
  stage8w(lds + 16384, gsrc + 16384, w, lane);
}

// 256-thread staging (K3): one 16KB chunk, 4 per thread.
__device__ __forceinline__ void stage16k(char* ldsbase, const char* gsrc, int w, int lane) {
#pragma unroll
  for (int j = 0; j < 4; ++j) {
    int off = j * 4096 + w * 1024;
    __builtin_amdgcn_global_load_lds((const as1_u32*)(gsrc + off + lane * 16),
                                     (as3_u32*)(ldsbase + off), 16, 0, 0);
  }
}

// xa loads for one kc (8 x global b128 per wave).
__device__ __forceinline__ void load_xa(short8* xa, const char* xb, int l15, int g) {
#pragma unroll
  for (int mt = 0; mt < 4; ++mt)
#pragma unroll
    for (int ks = 0; ks < 2; ++ks)
      xa[mt * 2 + ks] = *(const short8*)(xb + (ks * 4 + g) * 1024 +
                                         (mt * 16 + l15) * 16);
}

// One kc body: stage kc+1 + load xa(kc+1), counted wait, barrier, 24 MFMAs.
__device__ __forceinline__ void kc_body(int h, int kc, const char* wq,
                                        const char* xb, char* RING,
                                        int w, int lane, int brow,
                                        int us0, int us1, int l15, int g,
                                        short8* cur, short8* nxt,
                                        f32x4* aq, f32x4* ak, f32x4* av) {
  if (kc < 7) {
    stage24(RING + ((kc + 1) & 1) * 24576,
            wq + (size_t)(h * 24 + (kc + 1) * 3) * 8192, w, lane);
    load_xa(nxt, xb + (size_t)(kc + 1) * 8192, l15, g);
    VMCNT11;
  } else {
    VMCNT0;
  }
  BARR();
  const char* slot = RING + (kc & 1) * 24576;
  PRIO1;
#pragma unroll
  for (int rg = 0; rg < 3; ++rg) {
    const char* wsl = slot + rg * 8192;
    short8 bf0 = *(const short8*)(wsl + brow * 128 + us0);
    short8 bf1 = *(const short8*)(wsl + brow * 128 + us1);
    f32x4* acc = (rg == 0) ? aq : (rg == 1) ? ak : av;
#pragma unroll
    for (int mt = 0; mt < 4; ++mt) {
      acc[mt] = mfma16(cur[mt * 2], bf0, acc[mt]);
      acc[mt] = mfma16(cur[mt * 2 + 1], bf1, acc[mt]);
    }
  }
  PRIO0;
}

// ============================ prep (verbatim r11) ==========================
__global__ void prep_kernel(const float* __restrict__ x,
                            const float* __restrict__ wqkv_f,
                            const float* __restrict__ wo_f,
                            const float* __restrict__ rel,
                            unsigned short* __restrict__ wt,
                            float* __restrict__ bias2d,
                            char* __restrict__ dout) {
  int b = blockIdx.x, tid = threadIdx.x;
  if (b < 8192) {
    int n = b >> 2, p = b & 3;
    char* dstb = dout + (size_t)n * 131072 + 65536;
    const float* srcb = x + (size_t)n * 32768;
#pragma unroll
    for (int t = 0; t < 4; ++t) {
      int flat = t * 256 + tid;
      int c = p * 2 + (flat >> 9);
      int r512 = flat & 511;
      int row = r512 >> 3, u = r512 & 7;
      const float* src = srcb + row * 512 + c * 64 + u * 8;
      float4 a = *(const float4*)src;
      float4 cc = *(const float4*)(src + 4);
      unsigned p0 = (unsigned)f2bf(a.x) | ((unsigned)f2bf(a.y) << 16);
      unsigned p1 = (unsigned)f2bf(a.z) | ((unsigned)f2bf(a.w) << 16);
      unsigned p2 = (unsigned)f2bf(cc.x) | ((unsigned)f2bf(cc.y) << 16);
      unsigned p3 = (unsigned)f2bf(cc.z) | ((unsigned)f2bf(cc.w) << 16);
      *(uint4*)(dstb + c * 8192 + u * 1024 + row * 16) = make_uint4(p0, p1, p2, p3);
    }
  } else if (b < 8288) {
    int cb2 = (b - 8192) * 2;
#pragma unroll
    for (int t = 0; t < 4; ++t) {
      int flat = t * 256 + tid;
      int c = cb2 + (flat >> 9);
      int r512 = flat & 511;
      int row = r512 >> 3, us = r512 & 7;
      int kg = us ^ (row & 7);
      int h = c / 24, j = c % 24;
      int kc = j / 3, rg = j % 3;
      const float* src =
          wqkv_f + (size_t)(rg * 512 + h * 64 + row) * 512 + kc * 64 + kg * 8;
      float4 a = *(const float4*)src;
      float4 cc = *(const float4*)(src + 4);
      unsigned p0 = (unsigned)f2bf(a.x) | ((unsigned)f2bf(a.y) << 16);
      unsigned p1 = (unsigned)f2bf(a.z) | ((unsigned)f2bf(a.w) << 16);
      unsigned p2 = (unsigned)f2bf(cc.x) | ((unsigned)f2bf(cc.y) << 16);
      unsigned p3 = (unsigned)f2bf(cc.z) | ((unsigned)f2bf(cc.w) << 16);
      *(uint4*)(wt + (size_t)c * 4096 + r512 * 8) = make_uint4(p0, p1, p2, p3);
    }
  } else if (b < 8320) {
    int cw = b - 8288;
    unsigned short* dst = wt + 786432 + (size_t)cw * 8192;
#pragma unroll
    for (int t = 0; t < 4; ++t) {
      int u = t * 256 + tid;
      int row = u >> 4, us = u & 15;
      int kg = (us & 8) | ((us ^ row) & 7);
      int kcw = cw >> 3, ng = cw & 7;
      const float* src = wo_f + (size_t)(ng * 64 + row) * 512 + kcw * 128 + kg * 8;
      float4 a = *(const float4*)src;
      float4 cc = *(const float4*)(src + 4);
      unsigned p0 = (unsigned)f2bf(a.x) | ((unsigned)f2bf(a.y) << 16);
      unsigned p1 = (unsigned)f2bf(a.z) | ((unsigned)f2bf(a.w) << 16);
      unsigned p2 = (unsigned)f2bf(cc.x) | ((unsigned)f2bf(cc.y) << 16);
      unsigned p3 = (unsigned)f2bf(cc.z) | ((unsigned)f2bf(cc.w) << 16);
      *(uint4*)(dst + u * 8) = make_uint4(p0, p1, p2, p3);
    }
  } else {
    int idx = (b - 8320) * 256 + tid;
    int m = idx >> 6, nn = idx & 63;
    float s = 0.f;
#pragma unroll
    for (int hh = 0; hh < 8; ++hh) s += rel[hh * 16384 + m * 128 + nn];
    bias2d[idx] = s * 0.125f;
  }
}

// ============================ K2: attn_qkv2 ================================
__global__ __launch_bounds__(512) void attn_qkv2(
    const char* __restrict__ wq,        // 192 x 8KB QKV chunks (kc-major)
    const float* __restrict__ bqkv,     // [1536]
    const float* __restrict__ bias2d,   // [64,64]
    char* __restrict__ ctxg) {          // d_out stripes: [ctx 64KB | xbf 64KB]
  // Static LDS (compiler-visible -> 2 blocks/CU, VGPR budget honest):
  // RING 2 x 24KB [0,49152)  — attn scratch OVERLAYS it (ring idle in attn):
  //   seq ws scratch = smem + ws*24576: B0 +0, B1 +8192, B2 +16384.
  // BQ (bqkv copy) [49152, 55296).
  __shared__ __attribute__((aligned(16))) char smem[55296];
  char* RING = smem;
  float* BQ  = (float*)(smem + 49152);

  const int tid = threadIdx.x;
  const int w = tid >> 6, lane = tid & 63;
  const int l15 = lane & 15, g = lane >> 4;
  const int ws = w >> 2;               // seq-group (0/1)
  const int wn = w & 3;                // N-group within seq (16 cols)
  const int n0 = blockIdx.x * 2;

  const char* xb = ctxg + (size_t)(n0 + ws) * 131072 + 65536;  // seq's xbf
  char* B0 = smem + ws * 24576;
  char* B1 = B0 + 8192;
  char* B2 = B0 + 16384;

  const int brow = wn * 16 + l15;      // weight out-col (B-frag LDS row)
  const int us0 = (g ^ (brow & 7)) * 16;
  const int us1 = ((4 + g) ^ (brow & 7)) * 16;
  const int mrow = wn * 16 + g * 4;    // attn C rows (within seq)
  const int wrow = wn * 16 + l15;      // attn A row

  // ---- preamble: bqkv -> LDS; drain.
#pragma unroll
  for (int i = 0; i < 3; ++i) BQ[i * 512 + tid] = bqkv[i * 512 + tid];
  VMCNT0; LGKM0; BARR();

  short8 xaA[8], xaB[8];
  // prologue: kc0 of h=0 (3 stages + 8 xa)
  stage24(RING, wq, w, lane);
  load_xa(xaA, xb, l15, g);

  for (int h = 0; h < 8; ++h) {
    f32x4 aq[4] = {}, ak[4] = {}, av[4] = {};
#pragma unroll
    for (int kp = 0; kp < 4; ++kp) {
      kc_body(h, kp * 2, wq, xb, RING, w, lane, brow, us0, us1, l15, g,
              xaA, xaB, aq, ak, av);
      kc_body(h, kp * 2 + 1, wq, xb, RING, w, lane, brow, us0, us1, l15, g,
              xaB, xaA, aq, ak, av);
    }
    BARR();   // all waves done reading ring before it becomes attn scratch

    // ---- b2d bias loads (consumed after scores MFMA; long latency cover)
    float b2dv[16];
#pragma unroll
    for (int nt = 0; nt < 4; ++nt)
#pragma unroll
      for (int r = 0; r < 4; ++r)
        b2dv[nt * 4 + r] = bias2d[(mrow + r) * 64 + nt * 16 + l15];

    // ---------- head writeback: Q->B0, K->B1, Vt->B2 (per seq-group) ------
    {
      int col = wn * 16 + l15;
      float bq = BQ[h * 64 + col];
      float bk = BQ[512 + h * 64 + col];
      float bv = BQ[1024 + h * 64 + col];
#pragma unroll
      for (int mt = 0; mt < 4; ++mt) {
        int rowb = mt * 16 + g * 4;
#pragma unroll
        for (int r = 0; r < 4; ++r) {
          wr2s(B0, rowb + r, col, f2bf(aq[mt][r] + bq));
          wr2s(B1, rowb + r, col, f2bf(ak[mt][r] + bk));
        }
        unsigned short p0 = f2bf(av[mt][0] + bv);
        unsigned short p1 = f2bf(av[mt][1] + bv);
        unsigned short p2 = f2bf(av[mt][2] + bv);
        unsigned short p3 = f2bf(av[mt][3] + bv);
        unsigned lo = (unsigned)p0 | ((unsigned)p1 << 16);
        unsigned hi = (unsigned)p2 | ((unsigned)p3 << 16);
        wr8s(B2, col, rowb, make_uint2(lo, hi));   // Vt[d][tok]
      }
    }
    LGKM0; BARR();   // Q/K/Vt visible to the group's 4 waves

    // ---- scores + softmax: P -> B0 (wave-own rows)
    {
      f32x4 sc[4] = {};
      short8 aq0 = rd8s(B0, wrow, g);
      short8 aq1 = rd8s(B0, wrow, 4 + g);
#pragma unroll
      for (int nt = 0; nt < 4; ++nt)
        sc[nt] = mfma16(aq0, rd8s(B1, nt * 16 + l15, g), sc[nt]);
#pragma unroll
      for (int nt = 0; nt < 4; ++nt)
        sc[nt] = mfma16(aq1, rd8s(B1, nt * 16 + l15, 4 + g), sc[nt]);
      float mx[4] = {-1e30f, -1e30f, -1e30f, -1e30f};
#pragma unroll
      for (int nt = 0; nt < 4; ++nt)
#pragma unroll
        for (int r = 0; r < 4; ++r) {
          float v = sc[nt][r] * 0.125f + b2dv[nt * 4 + r];
          sc[nt][r] = v;
          mx[r] = fmaxf(mx[r], v);
        }
#pragma unroll
      for (int mk = 1; mk < 16; mk <<= 1)
#pragma unroll
        for (int r = 0; r < 4; ++r) mx[r] = fmaxf(mx[r], __shfl_xor(mx[r], mk));
      float sm[4] = {0.f, 0.f, 0.f, 0.f};
#pragma unroll
      for (int nt = 0; nt < 4; ++nt)
#pragma unroll
        for (int r = 0; r < 4; ++r) {
          float e = __expf(sc[nt][r] - mx[r]);
          sc[nt][r] = e;
          sm[r] += e;
        }
#pragma unroll
      for (int mk = 1; mk < 16; mk <<= 1)
#pragma unroll
        for (int r = 0; r < 4; ++r) sm[r] += __shfl_xor(sm[r], mk);
      float inv[4];
#pragma unroll
      for (int r = 0; r < 4; ++r) inv[r] = 1.0f / sm[r];
#pragma unroll
      for (int nt = 0; nt < 4; ++nt)
#pragma unroll
        for (int r = 0; r < 4; ++r)
          wr2s(B0, mrow + r, nt * 16 + l15, f2bf(sc[nt][r] * inv[r]));
    }

    // ---- PV (P own rows in-wave; Vt stable since writeback barrier)
    f32x4 cv[4] = {};
    {
      short8 ap0 = rd8s(B0, wrow, g);
      short8 ap1 = rd8s(B0, wrow, 4 + g);
#pragma unroll
      for (int nt = 0; nt < 4; ++nt)
        cv[nt] = mfma16(ap0, rd8s(B2, nt * 16 + l15, g), cv[nt]);
#pragma unroll
      for (int nt = 0; nt < 4; ++nt)
        cv[nt] = mfma16(ap1, rd8s(B2, nt * 16 + l15, 4 + g), cv[nt]);
    }
    BARR();   // all waves' scores/PV reads done before ctx overwrites B1
#pragma unroll
    for (int nt = 0; nt < 4; ++nt)
#pragma unroll
      for (int r = 0; r < 4; ++r)
        wr2s(B1, mrow + r, nt * 16 + l15, f2bf(cv[nt][r]));
    LGKM0; BARR();

    // ---- ctx copyout: contiguous 8KB/head into stripe front half
    {
      char* cdst = ctxg + (size_t)(n0 + ws) * 131072 + h * 8192;
      int gt = tid & 255;
#pragma unroll
      for (int it = 0; it < 2; ++it) {
        int flat = it * 256 + gt;
        int row = flat >> 3, s = flat & 7;
        uint4 v = *(const uint4*)(B1 + row * 128 + s * 16);
        *(uint4*)(cdst + row * 128 + s * 16) = v;
      }
    }
    BARR();   // copyout reads of ring-scratch done before next head's DMA
    if (h < 7) {   // stage next head's kc0 + xa0
      stage24(RING, wq + (size_t)((h + 1) * 24) * 8192, w, lane);
      load_xa(xaA, xb, l15, g);
    }
  }
}

// ============================ K3: oproj_ln (verbatim) ======================
__global__ __launch_bounds__(256, 2) void oproj_ln(
    const char* __restrict__ ctxg,
    const char* __restrict__ wo,
    const float* __restrict__ bo,
    const float* __restrict__ x,
    const float* __restrict__ lng,
    const float* __restrict__ lnb,
    float* __restrict__ out) {
  __shared__ __attribute__((aligned(16))) char smem[65536];
  char* WB = smem;
  char* CB = smem + 32768;
  float* EP  = (float*)smem;
  float* SM1 = (float*)(smem + 32768);
  float* SM2 = (float*)(smem + 33408);

  const int n = blockIdx.x;
  const int tid = threadIdx.x;
  const int w = tid >> 6, lane = tid & 63;
  const int l15 = lane & 15, g = lane >> 4;
  const int um = w >> 1, un = w & 1;

  const char* cbase = ctxg + (size_t)n * 131072;

  stage16k(CB, cbase, w, lane);
  stage16k(WB, wo, w, lane);

  f32x4 acc[8][2][2] = {};

  for (int kc = 0; kc < 4; ++kc) {
    short8 actx[2][4];
#pragma unroll
    for (int ng = 0; ng < 8; ++ng) {
      int b = kc * 8 + ng;
      if (b < 31)
        stage16k(WB + (((b + 1) & 1) << 14), wo + (size_t)(b + 1) * 16384, w, lane);
      if ((ng & 1) == 0 && kc < 3) {
        int p = ng >> 1;
        int off = p * 4096 + w * 1024;
        __builtin_amdgcn_global_load_lds(
            (const as1_u32*)(cbase + (kc + 1) * 16384 + off + lane * 16),
            (as3_u32*)(CB + (((kc + 1) & 1) << 14) + off), 16, 0, 0);
      }
      if (b < 31) { VMCNT5; } else { VMCNT0; }
      BARR();
      const char* cb = CB + ((kc & 1) << 14);
      if (ng == 0) {
#pragma unroll
        for (int mt = 0; mt < 2; ++mt)
#pragma unroll
          for (int ks = 0; ks < 4; ++ks) {
            int row = um * 32 + mt * 16 + l15;
            int u = ks * 4 + g;
            actx[mt][ks] = *(const short8*)(cb + (u >> 3) * 8192 + row * 128 +
                                            (((u & 7) ^ (row & 7)) * 16));
          }
      }
      const char* wsl = WB + ((b & 1) << 14);
      PRIO1;
#pragma unroll
      for (int ks = 0; ks < 4; ++ks) {
#pragma unroll
        for (int nt = 0; nt < 2; ++nt) {
          int row = un * 32 + nt * 16 + l15;
          int kg = ks * 4 + g;
          int us = (kg & 8) | ((kg ^ row) & 7);
          short8 bfr = *(const short8*)(wsl + row * 256 + us * 16);
          acc[ng][0][nt] = mfma16(actx[0][ks], bfr, acc[ng][0][nt]);
          acc[ng][1][nt] = mfma16(actx[1][ks], bfr, acc[ng][1][nt]);
        }
      }
      PRIO0;
      BARR();
    }
  }

  VMCNT0;
  const float* xblk = x + (size_t)n * 32768;
  float* oblk = out + (size_t)n * 32768;
  float s1[2][4] = {}, s2[2][4] = {};

#pragma unroll
  for (int ng = 0; ng < 8; ++ng) {
#pragma unroll
    for (int t = 0; t < 4; ++t) {
      int flat = t * 256 + tid;
      int row = flat >> 4, f4 = flat & 15;
      float4 v = *(const float4*)(xblk + row * 512 + ng * 64 + f4 * 4);
      *(float4*)(EP + row * 68 + f4 * 4) = v;
    }
    LGKM0; BARR();
    float boA[2];
#pragma unroll
    for (int nt = 0; nt < 2; ++nt) boA[nt] = bo[ng * 64 + un * 32 + nt * 16 + l15];
#pragma unroll
    for (int mt = 0; mt < 2; ++mt)
#pragma unroll
      for (int nt = 0; nt < 2; ++nt)
#pragma unroll
        for (int r = 0; r < 4; ++r) {
          int row = um * 32 + mt * 16 + g * 4 + r;
          float xv = EP[row * 68 + un * 32 + nt * 16 + l15];
          float v = acc[ng][mt][nt][r] + boA[nt] + xv;
          acc[ng][mt][nt][r] = v;
          s1[mt][r] += v;
          s2[mt][r] += v * v;
        }
    LGKM0; BARR();
  }
#pragma unroll
  for (int mk = 1; mk < 16; mk <<= 1)
#pragma unroll
    for (int mt = 0; mt < 2; ++mt)
#pragma unroll
      for (int r = 0; r < 4; ++r) {
        s1[mt][r] += __shfl_xor(s1[mt][r], mk);
        s2[mt][r] += __shfl_xor(s2[mt][r], mk);
      }
  if (l15 == 0) {
#pragma unroll
    for (int mt = 0; mt < 2; ++mt)
#pragma unroll
      for (int r = 0; r < 4; ++r) {
        int row = um * 32 + mt * 16 + g * 4 + r;
        SM1[row * 2 + un] = s1[mt][r];
        SM2[row * 2 + un] = s2[mt][r];
      }
  }
  LGKM0; BARR();
  float mu[2][4], rs[2][4];
#pragma unroll
  for (int mt = 0; mt < 2; ++mt)
#pragma unroll
    for (int r = 0; r < 4; ++r) {
      int row = um * 32 + mt * 16 + g * 4 + r;
      float a1 = SM1[row * 2] + SM1[row * 2 + 1];
      float a2 = SM2[row * 2] + SM2[row * 2 + 1];
      float m = a1 * (1.0f / 512.0f);
      float var = a2 * (1.0f / 512.0f) - m * m;
      mu[mt][r] = m;
      rs[mt][r] = rsqrtf(var + 1e-5f);
    }
  BARR();
#pragma unroll
  for (int ng = 0; ng < 8; ++ng) {
    float lgA[2], lbA[2];
#pragma unroll
    for (int nt = 0; nt < 2; ++nt) {
      int col = ng * 64 + un * 32 + nt * 16 + l15;
      lgA[nt] = lng[col];
      lbA[nt] = lnb[col];
    }
#pragma unroll
    for (int mt = 0; mt < 2; ++mt)
#pragma unroll
      for (int nt = 0; nt < 2; ++nt)
#pragma unroll
        for (int r = 0; r < 4; ++r) {
          int row = um * 32 + mt * 16 + g * 4 + r;
          EP[row * 68 + un * 32 + nt * 16 + l15] =
              (acc[ng][mt][nt][r] - mu[mt][r]) * rs[mt][r] * lgA[nt] + lbA[nt];
        }
    LGKM0; BARR();
#pragma unroll
    for (int t = 0; t < 4; ++t) {
      int flat = t * 256 + tid;
      int row = flat >> 4, f4 = flat & 15;
      *(float4*)(oblk + row * 512 + ng * 64 + f4 * 4) =
          *(const float4*)(EP + row * 68 + f4 * 4);
    }
    BARR();
  }
}

// ============================ launch =======================================
extern "C" void kernel_launch(void* const* d_in, const int* in_sizes, int n_in,
                              void* d_out, int out_size, void* d_ws, size_t ws_size,
                              hipStream_t stream) {
  const float* x    = (const float*)d_in[0];
  const float* wqkv = (const float*)d_in[1];
  const float* bqkv = (const float*)d_in[2];
  const float* wo   = (const float*)d_in[3];
  const float* bo   = (const float*)d_in[4];
  const float* lng  = (const float*)d_in[5];
  const float* lnb  = (const float*)d_in[6];
  const float* rel  = (const float*)d_in[7];

  // ws: 192 QKV 8KB chunks [0,1572864) | 32 Wo 16KB chunks | bias2d @2097152
  unsigned short* wt = (unsigned short*)d_ws;
  float* bias2d = (float*)((char*)d_ws + 2097152);
  const char* wqc = (const char*)d_ws;
  const char* woc = (const char*)d_ws + 1572864;

  prep_kernel<<<8336, 256, 0, stream>>>(x, wqkv, wo, rel, wt, bias2d,
                                        (char*)d_out);
  attn_qkv2<<<1024, 512, 0, stream>>>(wqc, bqkv, bias2d, (char*)d_out);
  oproj_ln<<<2048, 256, 0, stream>>>((const char*)d_out, woc, bo, x, lng, lnb,
                                     (float*)d_out);
}

// Round 13
// 556.797 us; speedup vs baseline: 1.5991x; 1.5991x over previous
//
#include <hip/hip_runtime.h>
#include <stdint.h>
#include <stddef.h>

// ---------------------------------------------------------------------------
// EnhancedSpatialAttention, round 13 (MI355X / gfx950).
// = round 11's attn_qkv2 (proven: 334us, VGPR 112, no spill) + ONE change:
//   attn scratch OVERLAYS the weight ring + XB stage -> static LDS 54KB ->
//   2 blocks/CU (4 waves/SIMD) instead of r11's 104KB dynamic -> 1 block/CU.
//   Ring restaged per head after copyout (counted waits re-derived; tail
//   kc=7: Q vmcnt(1), V vmcnt(0); post-restage = prologue pattern).
// r12's xa register double-buffer is REVERTED (it caused 128-VGPR spill).
// prep / oproj_ln: verbatim (proven).
// ---------------------------------------------------------------------------

typedef __attribute__((ext_vector_type(8))) short short8;    // 8 bf16
typedef __attribute__((ext_vector_type(4))) float f32x4;     // MFMA C/D frag

typedef __attribute__((address_space(3))) unsigned int as3_u32;
typedef __attribute__((address_space(1))) unsigned int as1_u32;

#define VMCNT5  asm volatile("s_waitcnt vmcnt(5)" ::: "memory")
#define VMCNT2  asm volatile("s_waitcnt vmcnt(2)" ::: "memory")
#define VMCNT1  asm volatile("s_waitcnt vmcnt(1)" ::: "memory")
#define VMCNT0  asm volatile("s_waitcnt vmcnt(0)" ::: "memory")
#define LGKM0   asm volatile("s_waitcnt lgkmcnt(0)" ::: "memory")
#define BARR()  __builtin_amdgcn_s_barrier()
#define PRIO1   __builtin_amdgcn_s_setprio(1)
#define PRIO0   __builtin_amdgcn_s_setprio(0)

__device__ __forceinline__ unsigned short f2bf(float f) {
  unsigned u = __builtin_bit_cast(unsigned, f);
  u = (u + 0x7FFFu + ((u >> 16) & 1u)) >> 16;   // RNE
  return (unsigned short)u;
}

__device__ __forceinline__ f32x4 mfma16(short8 a, short8 b, f32x4 c) {
  return __builtin_amdgcn_mfma_f32_16x16x32_bf16(a, b, c, 0, 0, 0);
}

// 64-row x 64-col bf16 scratch, 128B row stride, 16B-unit XOR swizzle.
__device__ __forceinline__ short8 rd8s(const char* buf, int row, int unit) {
  return *(const short8*)(buf + row * 128 + ((unit ^ (row & 7)) * 16));
}
__device__ __forceinline__ void wr2s(char* buf, int row, int col, unsigned short v) {
  int slot = (col >> 3) ^ (row & 7);
  *(unsigned short*)(buf + row * 128 + slot * 16 + (col & 7) * 2) = v;
}
__device__ __forceinline__ void wr8s(char* buf, int row, int col, uint2 v) {
  int slot = (col >> 3) ^ (row & 7);
  *(uint2*)(buf + row * 128 + slot * 16 + (col & 7) * 2) = v;
}

// 512-thread staging: one 8KB chunk, 1 global_load_lds per thread.
__device__ __forceinline__ void stage8w(char* lds, const char* gsrc, int w, int lane) {
  __builtin_amdgcn_global_load_lds((const as1_u32*)(gsrc + w * 1024 + lane * 16),
                                   (as3_u32*)(lds + w * 1024), 16, 0, 0);
}

// 256-thread staging (K3): one 16KB chunk, 4 per thread.
__device__ __forceinline__ void stage16k(char* ldsbase, const char* gsrc, int w, int lane) {
#pragma unroll
  for (int j = 0; j < 4; ++j) {
    int off = j * 4096 + w * 1024;
    __builtin_amdgcn_global_load_lds((const as1_u32*)(gsrc + off + lane * 16),
                                     (as3_u32*)(ldsbase + off), 16, 0, 0);
  }
}

// ============================ prep (verbatim) ==============================
__global__ void prep_kernel(const float* __restrict__ x,
                            const float* __restrict__ wqkv_f,
                            const float* __restrict__ wo_f,
                            const float* __restrict__ rel,
                            unsigned short* __restrict__ wt,
                            float* __restrict__ bias2d,
                            char* __restrict__ dout) {
  int b = blockIdx.x, tid = threadIdx.x;
  if (b < 8192) {
    int n = b >> 2, p = b & 3;
    char* dstb = dout + (size_t)n * 131072 + 65536;
    const float* srcb = x + (size_t)n * 32768;
#pragma unroll
    for (int t = 0; t < 4; ++t) {
      int flat = t * 256 + tid;
      int c = p * 2 + (flat >> 9);
      int r512 = flat & 511;
      int row = r512 >> 3, u = r512 & 7;
      const float* src = srcb + row * 512 + c * 64 + u * 8;
      float4 a = *(const float4*)src;
      float4 cc = *(const float4*)(src + 4);
      unsigned p0 = (unsigned)f2bf(a.x) | ((unsigned)f2bf(a.y) << 16);
      unsigned p1 = (unsigned)f2bf(a.z) | ((unsigned)f2bf(a.w) << 16);
      unsigned p2 = (unsigned)f2bf(cc.x) | ((unsigned)f2bf(cc.y) << 16);
      unsigned p3 = (unsigned)f2bf(cc.z) | ((unsigned)f2bf(cc.w) << 16);
      *(uint4*)(dstb + c * 8192 + u * 1024 + row * 16) = make_uint4(p0, p1, p2, p3);
    }
  } else if (b < 8288) {
    int cb2 = (b - 8192) * 2;
#pragma unroll
    for (int t = 0; t < 4; ++t) {
      int flat = t * 256 + tid;
      int c = cb2 + (flat >> 9);
      int r512 = flat & 511;
      int row = r512 >> 3, us = r512 & 7;
      int kg = us ^ (row & 7);
      int h = c / 24, j = c % 24;
      int kc = j / 3, rg = j % 3;
      const float* src =
          wqkv_f + (size_t)(rg * 512 + h * 64 + row) * 512 + kc * 64 + kg * 8;
      float4 a = *(const float4*)src;
      float4 cc = *(const float4*)(src + 4);
      unsigned p0 = (unsigned)f2bf(a.x) | ((unsigned)f2bf(a.y) << 16);
      unsigned p1 = (unsigned)f2bf(a.z) | ((unsigned)f2bf(a.w) << 16);
      unsigned p2 = (unsigned)f2bf(cc.x) | ((unsigned)f2bf(cc.y) << 16);
      unsigned p3 = (unsigned)f2bf(cc.z) | ((unsigned)f2bf(cc.w) << 16);
      *(uint4*)(wt + (size_t)c * 4096 + r512 * 8) = make_uint4(p0, p1, p2, p3);
    }
  } else if (b < 8320) {
    int cw = b - 8288;
    unsigned short* dst = wt + 786432 + (size_t)cw * 8192;
#pragma unroll
    for (int t = 0; t < 4; ++t) {
      int u = t * 256 + tid;
      int row = u >> 4, us = u & 15;
      int kg = (us & 8) | ((us ^ row) & 7);
      int kcw = cw >> 3, ng = cw & 7;
      const float* src = wo_f + (size_t)(ng * 64 + row) * 512 + kcw * 128 + kg * 8;
      float4 a = *(const float4*)src;
      float4 cc = *(const float4*)(src + 4);
      unsigned p0 = (unsigned)f2bf(a.x) | ((unsigned)f2bf(a.y) << 16);
      unsigned p1 = (unsigned)f2bf(a.z) | ((unsigned)f2bf(a.w) << 16);
      unsigned p2 = (unsigned)f2bf(cc.x) | ((unsigned)f2bf(cc.y) << 16);
      unsigned p3 = (unsigned)f2bf(cc.z) | ((unsigned)f2bf(cc.w) << 16);
      *(uint4*)(dst + u * 8) = make_uint4(p0, p1, p2, p3);
    }
  } else {
    int idx = (b - 8320) * 256 + tid;
    int m = idx >> 6, nn = idx & 63;
    float s = 0.f;
#pragma unroll
    for (int hh = 0; hh < 8; ++hh) s += rel[hh * 16384 + m * 128 + nn];
    bias2d[idx] = s * 0.125f;
  }
}

// ============================ K2: attn_qkv2 ================================
__global__ __launch_bounds__(512) void attn_qkv2(
    const char* __restrict__ wq,        // 192 x 8KB QKV chunks (kc-major)
    const float* __restrict__ bqkv,     // [1536]
    const float* __restrict__ bias2d,   // [64,64]
    char* __restrict__ ctxg) {          // d_out stripes: [ctx 64KB | xbf 64KB]
  // Static LDS 54KB -> 2 blocks/CU:
  //   RING 4 x 8KB [0,32768) | XB 2 x 8KB [32768,49152) | BQ [49152,55296)
  //   attn scratch OVERLAYS [0,49152): seq ws base = ws*24576,
  //   B0 +0, B1 +8192, B2 +16384.
  __shared__ __attribute__((aligned(16))) char smem[55296];
  char* RING = smem;
  char* XB   = smem + 32768;
  float* BQ  = (float*)(smem + 49152);

  const int tid = threadIdx.x;
  const int w = tid >> 6, lane = tid & 63;
  const int l15 = lane & 15, g = lane >> 4;
  const int ws = w >> 2;               // seq-group (0/1)
  const int wn = w & 3;                // N-group within seq (16 cols)
  const int n0 = blockIdx.x * 2;

  const char* x0 = ctxg + (size_t)n0 * 131072 + 65536;
  const char* x1 = x0 + 131072;
  char* B0 = smem + ws * 24576;
  char* B1 = B0 + 8192;
  char* B2 = B0 + 16384;

  const int brow = wn * 16 + l15;      // weight out-col (B-frag LDS row)
  const int us0 = (g ^ (brow & 7)) * 16;
  const int us1 = ((4 + g) ^ (brow & 7)) * 16;
  const int mrow = wn * 16 + g * 4;    // attn C rows (within seq)
  const int wrow = wn * 16 + l15;      // attn A row

  // ---- preamble: bqkv -> LDS, bias2d -> regs, drain.
#pragma unroll
  for (int i = 0; i < 3; ++i) BQ[i * 512 + tid] = bqkv[i * 512 + tid];
  float b2d[16];
#pragma unroll
  for (int nt = 0; nt < 4; ++nt)
#pragma unroll
    for (int r = 0; r < 4; ++r)
      b2d[nt * 4 + r] = bias2d[(mrow + r) * 64 + nt * 16 + l15];
  VMCNT0; LGKM0; BARR();

  // prologue: X(0) then W0,W1,W2
  stage8w(XB, x0, w, lane);
  stage8w(XB + 8192, x1, w, lane);
  stage8w(RING, wq, w, lane);
  stage8w(RING + 8192, wq + 8192, w, lane);
  stage8w(RING + 16384, wq + 16384, w, lane);

  for (int h = 0; h < 8; ++h) {
    f32x4 aq[4] = {}, ak[4] = {}, av[4] = {};
#pragma unroll
    for (int kc = 0; kc < 8; ++kc) {
      const int j = h * 24 + kc * 3;
      const int sQ = (kc * 3) & 3, sK = (kc * 3 + 1) & 3, sV = (kc * 3 + 2) & 3;
      const int tQ = (kc * 3 + 3) & 3, tK = (kc * 3 + 4) & 3, tV = (kc * 3 + 5) & 3;
      // ================= Q body: consume W(j) + X(kc) =================
      if (kc < 7) {
        stage8w(RING + tQ * 8192, wq + (size_t)(j + 3) * 8192, w, lane);
        VMCNT2;
      } else {
        VMCNT1;   // leaves W(j+2); X(kc) + W(j) landed
      }
      BARR();
      short8 xa[8];
      { const char* xb = XB + ws * 8192;
#pragma unroll
        for (int mt = 0; mt < 4; ++mt)
#pragma unroll
          for (int ks = 0; ks < 2; ++ks)
            xa[mt * 2 + ks] = *(const short8*)(xb + (ks * 4 + g) * 1024 +
                                               (mt * 16 + l15) * 16);
      }
      {
        const char* wsl = RING + sQ * 8192;
        short8 bf0 = *(const short8*)(wsl + brow * 128 + us0);
        short8 bf1 = *(const short8*)(wsl + brow * 128 + us1);
        PRIO1;
#pragma unroll
        for (int mt = 0; mt < 4; ++mt) {
          aq[mt] = mfma16(xa[mt * 2], bf0, aq[mt]);
          aq[mt] = mfma16(xa[mt * 2 + 1], bf1, aq[mt]);
        }
        PRIO0;
      }
      // ================= K body: consume W(j+1) =================
      if (kc < 7)
        stage8w(RING + tK * 8192, wq + (size_t)(j + 4) * 8192, w, lane);
      BARR();
      {
        const char* wsl = RING + sK * 8192;
        short8 bf0 = *(const short8*)(wsl + brow * 128 + us0);
        short8 bf1 = *(const short8*)(wsl + brow * 128 + us1);
        PRIO1;
#pragma unroll
        for (int mt = 0; mt < 4; ++mt) {
          ak[mt] = mfma16(xa[mt * 2], bf0, ak[mt]);
          ak[mt] = mfma16(xa[mt * 2 + 1], bf1, ak[mt]);
        }
        PRIO0;
      }
      if (kc < 7) {   // stage X(kc+1)
        stage8w(XB, x0 + (size_t)(kc + 1) * 8192, w, lane);
        stage8w(XB + 8192, x1 + (size_t)(kc + 1) * 8192, w, lane);
      }
      // ================= V body: consume W(j+2) =================
      if (kc < 7) {
        stage8w(RING + tV * 8192, wq + (size_t)(j + 5) * 8192, w, lane);
        VMCNT5;
      } else {
        VMCNT0;   // drain everything before ring becomes attn scratch
      }
      BARR();
      {
        const char* wsl = RING + sV * 8192;
        short8 bf0 = *(const short8*)(wsl + brow * 128 + us0);
        short8 bf1 = *(const short8*)(wsl + brow * 128 + us1);
        PRIO1;
#pragma unroll
        for (int mt = 0; mt < 4; ++mt) {
          av[mt] = mfma16(xa[mt * 2], bf0, av[mt]);
          av[mt] = mfma16(xa[mt * 2 + 1], bf1, av[mt]);
        }
        PRIO0;
      }
    }
    BARR();   // all waves done reading ring/XB -> safe to use as attn scratch

    // ---------- head writeback: Q->B0, K->B1, Vt->B2 (per seq-group) ------
    {
      int col = wn * 16 + l15;
      float bq = BQ[h * 64 + col];
      float bk = BQ[512 + h * 64 + col];
      float bv = BQ[1024 + h * 64 + col];
#pragma unroll
      for (int mt = 0; mt < 4; ++mt) {
        int rowb = mt * 16 + g * 4;
#pragma unroll
        for (int r = 0; r < 4; ++r) {
          wr2s(B0, rowb + r, col, f2bf(aq[mt][r] + bq));
          wr2s(B1, rowb + r, col, f2bf(ak[mt][r] + bk));
        }
        unsigned short p0 = f2bf(av[mt][0] + bv);
        unsigned short p1 = f2bf(av[mt][1] + bv);
        unsigned short p2 = f2bf(av[mt][2] + bv);
        unsigned short p3 = f2bf(av[mt][3] + bv);
        unsigned lo = (unsigned)p0 | ((unsigned)p1 << 16);
        unsigned hi = (unsigned)p2 | ((unsigned)p3 << 16);
        wr8s(B2, col, rowb, make_uint2(lo, hi));   // Vt[d][tok]
      }
    }
    LGKM0; BARR();   // Q/K/Vt visible to the group's 4 waves

    // ---- scores + softmax: P -> B0 (wave-own rows)
    {
      f32x4 sc[4] = {};
      short8 aq0 = rd8s(B0, wrow, g);
      short8 aq1 = rd8s(B0, wrow, 4 + g);
#pragma unroll
      for (int nt = 0; nt < 4; ++nt)
        sc[nt] = mfma16(aq0, rd8s(B1, nt * 16 + l15, g), sc[nt]);
#pragma unroll
      for (int nt = 0; nt < 4; ++nt)
        sc[nt] = mfma16(aq1, rd8s(B1, nt * 16 + l15, 4 + g), sc[nt]);
      float mx[4] = {-1e30f, -1e30f, -1e30f, -1e30f};
#pragma unroll
      for (int nt = 0; nt < 4; ++nt)
#pragma unroll
        for (int r = 0; r < 4; ++r) {
          float v = sc[nt][r] * 0.125f + b2d[nt * 4 + r];
          sc[nt][r] = v;
          mx[r] = fmaxf(mx[r], v);
        }
#pragma unroll
      for (int mk = 1; mk < 16; mk <<= 1)
#pragma unroll
        for (int r = 0; r < 4; ++r) mx[r] = fmaxf(mx[r], __shfl_xor(mx[r], mk));
      float sm[4] = {0.f, 0.f, 0.f, 0.f};
#pragma unroll
      for (int nt = 0; nt < 4; ++nt)
#pragma unroll
        for (int r = 0; r < 4; ++r) {
          float e = __expf(sc[nt][r] - mx[r]);
          sc[nt][r] = e;
          sm[r] += e;
        }
#pragma unroll
      for (int mk = 1; mk < 16; mk <<= 1)
#pragma unroll
        for (int r = 0; r < 4; ++r) sm[r] += __shfl_xor(sm[r], mk);
      float inv[4];
#pragma unroll
      for (int r = 0; r < 4; ++r) inv[r] = 1.0f / sm[r];
#pragma unroll
      for (int nt = 0; nt < 4; ++nt)
#pragma unroll
        for (int r = 0; r < 4; ++r)
          wr2s(B0, mrow + r, nt * 16 + l15, f2bf(sc[nt][r] * inv[r]));
    }

    // ---- PV (P own rows in-wave; Vt stable since writeback barrier)
    f32x4 cv[4] = {};
    {
      short8 ap0 = rd8s(B0, wrow, g);
      short8 ap1 = rd8s(B0, wrow, 4 + g);
#pragma unroll
      for (int nt = 0; nt < 4; ++nt)
        cv[nt] = mfma16(ap0, rd8s(B2, nt * 16 + l15, g), cv[nt]);
#pragma unroll
      for (int nt = 0; nt < 4; ++nt)
        cv[nt] = mfma16(ap1, rd8s(B2, nt * 16 + l15, 4 + g), cv[nt]);
    }
    BARR();   // all waves' scores/PV reads done before ctx overwrites B1
#pragma unroll
    for (int nt = 0; nt < 4; ++nt)
#pragma unroll
      for (int r = 0; r < 4; ++r)
        wr2s(B1, mrow + r, nt * 16 + l15, f2bf(cv[nt][r]));
    LGKM0; BARR();

    // ---- ctx copyout: contiguous 8KB/head into stripe front half
    {
      char* cdst = ctxg + (size_t)(n0 + ws) * 131072 + h * 8192;
      int gt = tid & 255;
#pragma unroll
      for (int it = 0; it < 2; ++it) {
        int flat = it * 256 + gt;
        int row = flat >> 3, s = flat & 7;
        uint4 v = *(const uint4*)(B1 + row * 128 + s * 16);
        *(uint4*)(cdst + row * 128 + s * 16) = v;
      }
    }
    BARR();   // copyout reads of overlay scratch done before restage DMA
    if (h < 7) {   // restage next head: X(0), W0..W2 (prologue pattern)
      const char* wn_ = wq + (size_t)((h + 1) * 24) * 8192;
      stage8w(XB, x0, w, lane);
      stage8w(XB + 8192, x1, w, lane);
      stage8w(RING, wn_, w, lane);
      stage8w(RING + 8192, wn_ + 8192, w, lane);
      stage8w(RING + 16384, wn_ + 16384, w, lane);
    }
  }
}

// ============================ K3: oproj_ln (verbatim) ======================
__global__ __launch_bounds__(256, 2) void oproj_ln(
    const char* __restrict__ ctxg,
    const char* __restrict__ wo,
    const float* __restrict__ bo,
    const float* __restrict__ x,
    const float* __restrict__ lng,
    const float* __restrict__ lnb,
    float* __restrict__ out) {
  __shared__ __attribute__((aligned(16))) char smem[65536];
  char* WB = smem;
  char* CB = smem + 32768;
  float* EP  = (float*)smem;
  float* SM1 = (float*)(smem + 32768);
  float* SM2 = (float*)(smem + 33408);

  const int n = blockIdx.x;
  const int tid = threadIdx.x;
  const int w = tid >> 6, lane = tid & 63;
  const int l15 = lane & 15, g = lane >> 4;
  const int um = w >> 1, un = w & 1;

  const char* cbase = ctxg + (size_t)n * 131072;

  stage16k(CB, cbase, w, lane);
  stage16k(WB, wo, w, lane);

  f32x4 acc[8][2][2] = {};

  for (int kc = 0; kc < 4; ++kc) {
    short8 actx[2][4];
#pragma unroll
    for (int ng = 0; ng < 8; ++ng) {
      int b = kc * 8 + ng;
      if (b < 31)
        stage16k(WB + (((b + 1) & 1) << 14), wo + (size_t)(b + 1) * 16384, w, lane);
      if ((ng & 1) == 0 && kc < 3) {
        int p = ng >> 1;
        int off = p * 4096 + w * 1024;
        __builtin_amdgcn_global_load_lds(
            (const as1_u32*)(cbase + (kc + 1) * 16384 + off + lane * 16),
            (as3_u32*)(CB + (((kc + 1) & 1) << 14) + off), 16, 0, 0);
      }
      if (b < 31) { VMCNT5; } else { VMCNT0; }
      BARR();
      const char* cb = CB + ((kc & 1) << 14);
      if (ng == 0) {
#pragma unroll
        for (int mt = 0; mt < 2; ++mt)
#pragma unroll
          for (int ks = 0; ks < 4; ++ks) {
            int row = um * 32 + mt * 16 + l15;
            int u = ks * 4 + g;
            actx[mt][ks] = *(const short8*)(cb + (u >> 3) * 8192 + row * 128 +
                                            (((u & 7) ^ (row & 7)) * 16));
          }
      }
      const char* wsl = WB + ((b & 1) << 14);
      PRIO1;
#pragma unroll
      for (int ks = 0; ks < 4; ++ks) {
#pragma unroll
        for (int nt = 0; nt < 2; ++nt) {
          int row = un * 32 + nt * 16 + l15;
          int kg = ks * 4 + g;
          int us = (kg & 8) | ((kg ^ row) & 7);
          short8 bfr = *(const short8*)(wsl + row * 256 + us * 16);
          acc[ng][0][nt] = mfma16(actx[0][ks], bfr, acc[ng][0][nt]);
          acc[ng][1][nt] = mfma16(actx[1][ks], bfr, acc[ng][1][nt]);
        }
      }
      PRIO0;
      BARR();
    }
  }

  VMCNT0;
  const float* xblk = x + (size_t)n * 32768;
  float* oblk = out + (size_t)n * 32768;
  float s1[2][4] = {}, s2[2][4] = {};

#pragma unroll
  for (int ng = 0; ng < 8; ++ng) {
#pragma unroll
    for (int t = 0; t < 4; ++t) {
      int flat = t * 256 + tid;
      int row = flat >> 4, f4 = flat & 15;
      float4 v = *(const float4*)(xblk + row * 512 + ng * 64 + f4 * 4);
      *(float4*)(EP + row * 68 + f4 * 4) = v;
    }
    LGKM0; BARR();
    float boA[2];
#pragma unroll
    for (int nt = 0; nt < 2; ++nt) boA[nt] = bo[ng * 64 + un * 32 + nt * 16 + l15];
#pragma unroll
    for (int mt = 0; mt < 2; ++mt)
#pragma unroll
      for (int nt = 0; nt < 2; ++nt)
#pragma unroll
        for (int r = 0; r < 4; ++r) {
          int row = um * 32 + mt * 16 + g * 4 + r;
          float xv = EP[row * 68 + un * 32 + nt * 16 + l15];
          float v = acc[ng][mt][nt][r] + boA[nt] + xv;
          acc[ng][mt][nt][r] = v;
          s1[mt][r] += v;
          s2[mt][r] += v * v;
        }
    LGKM0; BARR();
  }
#pragma unroll
  for (int mk = 1; mk < 16; mk <<= 1)
#pragma unroll
    for (int mt = 0; mt < 2; ++mt)
#pragma unroll
      for (int r = 0; r < 4; ++r) {
        s1[mt][r] += __shfl_xor(s1[mt][r], mk);
        s2[mt][r] += __shfl_xor(s2[mt][r], mk);
      }
  if (l15 == 0) {
#pragma unroll
    for (int mt = 0; mt < 2; ++mt)
#pragma unroll
      for (int r = 0; r < 4; ++r) {
        int row = um * 32 + mt * 16 + g * 4 + r;
        SM1[row * 2 + un] = s1[mt][r];
        SM2[row * 2 + un] = s2[mt][r];
      }
  }
  LGKM0; BARR();
  float mu[2][4], rs[2][4];
#pragma unroll
  for (int mt = 0; mt < 2; ++mt)
#pragma unroll
    for (int r = 0; r < 4; ++r) {
      int row = um * 32 + mt * 16 + g * 4 + r;
      float a1 = SM1[row * 2] + SM1[row * 2 + 1];
      float a2 = SM2[row * 2] + SM2[row * 2 + 1];
      float m = a1 * (1.0f / 512.0f);
      float var = a2 * (1.0f / 512.0f) - m * m;
      mu[mt][r] = m;
      rs[mt][r] = rsqrtf(var + 1e-5f);
    }
  BARR();
#pragma unroll
  for (int ng = 0; ng < 8; ++ng) {
    float lgA[2], lbA[2];
#pragma unroll
    for (int nt = 0; nt < 2; ++nt) {
      int col = ng * 64 + un * 32 + nt * 16 + l15;
      lgA[nt] = lng[col];
      lbA[nt] = lnb[col];
    }
#pragma unroll
    for (int mt = 0; mt < 2; ++mt)
#pragma unroll
      for (int nt = 0; nt < 2; ++nt)
#pragma unroll
        for (int r = 0; r < 4; ++r) {
          int row = um * 32 + mt * 16 + g * 4 + r;
          EP[row * 68 + un * 32 + nt * 16 + l15] =
              (acc[ng][mt][nt][r] - mu[mt][r]) * rs[mt][r] * lgA[nt] + lbA[nt];
        }
    LGKM0; BARR();
#pragma unroll
    for (int t = 0; t < 4; ++t) {
      int flat = t * 256 + tid;
      int row = flat >> 4, f4 = flat & 15;
      *(float4*)(oblk + row * 512 + ng * 64 + f4 * 4) =
          *(const float4*)(EP + row * 68 + f4 * 4);
    }
    BARR();
  }
}

// ============================ launch =======================================
extern "C" void kernel_launch(void* const* d_in, const int* in_sizes, int n_in,
                              void* d_out, int out_size, void* d_ws, size_t ws_size,
                              hipStream_t stream) {
  const float* x    = (const float*)d_in[0];
  const float* wqkv = (const float*)d_in[1];
  const float* bqkv = (const float*)d_in[2];
  const float* wo   = (const float*)d_in[3];
  const float* bo   = (const float*)d_in[4];
  const float* lng  = (const float*)d_in[5];
  const float* lnb  = (const float*)d_in[6];
  const float* rel  = (const float*)d_in[7];

  // ws: 192 QKV 8KB chunks [0,1572864) | 32 Wo 16KB chunks | bias2d @2097152
  unsigned short* wt = (unsigned short*)d_ws;
  float* bias2d = (float*)((char*)d_ws + 2097152);
  const char* wqc = (const char*)d_ws;
  const char* woc = (const char*)d_ws + 1572864;

  prep_kernel<<<8336, 256, 0, stream>>>(x, wqkv, wo, rel, wt, bias2d,
                                        (char*)d_out);
  attn_qkv2<<<1024, 512, 0, stream>>>(wqc, bqkv, bias2d, (char*)d_out);
  oproj_ln<<<2048, 256, 0, stream>>>((const char*)d_out, woc, bo, x, lng, lnb,
                                     (float*)d_out);
}